// Round 8
// baseline (195.398 us; speedup 1.0000x reference)
//
#include <hip/hip_runtime.h>

#define DIM 16
#define HID 256
#define NSTEPS 10
#define TILE_B 32
#define NTHR 1024
#define LSH 264      // bf16 LDS row stride, multiple of 8 shorts (16 B) for aligned bf16x8 reads.
                     // Tile swizzle: stored col' = col ^ (16 * bit3(row)).
                     // R23: PARALLEL PHASE 3 via K=16 MFMA, hazard-safe. R22's NaN was the raw
                     // inline-asm v_mfma: compiler inserts hazard s_nops only for BUILTINS, so
                     // the ds_write of cp read the MFMA dest before the 4-pass op retired.
                     // Now: __builtin_amdgcn_mfma_f32_16x16x16bf16_1k when available (compiler
                     // handles hazards); else asm with explicit s_nop padding inside the block.
                     // Structure unchanged from R22: each h-wave's fz partial = two chained K=16
                     // MFMAs per bt whose B operand is the lane's OWN silu output (B[k=4g+e][b=r]
                     // == cc[nt][bt][q] layout), A = w3t bf16x4 constants. No cross-lane ops,
                     // h2s deleted, partials in fzp[8][2][16][20], update waves sum 8 f32x4 + RK4.

typedef __attribute__((ext_vector_type(8))) short bf16x8;
typedef __attribute__((ext_vector_type(4))) short bf16x4;
typedef __attribute__((ext_vector_type(4))) float f32x4;
typedef __attribute__((ext_vector_type(2))) unsigned int u32x2;

__device__ __forceinline__ unsigned short f2bf(float f) {
    unsigned u = __float_as_uint(f);
    u += 0x7fff + ((u >> 16) & 1);          // RNE
    return (unsigned short)(u >> 16);
}
__device__ __forceinline__ float bfw_lo(unsigned u) { return __uint_as_float(u << 16); }
__device__ __forceinline__ float bfw_hi(unsigned u) { return __uint_as_float(u & 0xffff0000u); }
__device__ __forceinline__ unsigned packtr(float a, float b) {   // [bf16(b):bf16(a)], trunc
    return __builtin_amdgcn_perm(__float_as_uint(b), __float_as_uint(a), 0x07060302u);
}
__device__ __forceinline__ void silu_both(float x, float& h, float& d) {
    float s = __builtin_amdgcn_rcpf(1.0f + __expf(-x));
    h = x * s;
    d = fmaf(h, 1.0f - s, s);               // silu' = s + h*(1-s)
}

#if defined(__has_builtin) && __has_builtin(__builtin_amdgcn_mfma_f32_16x16x16bf16_1k)
__device__ __forceinline__ f32x4 mfma16(bf16x4 a, bf16x4 b, f32x4 c) {
    return __builtin_amdgcn_mfma_f32_16x16x16bf16_1k(a, b, c, 0, 0, 0);
}
#else
__device__ __forceinline__ f32x4 mfma16(bf16x4 a, bf16x4 b, f32x4 c) {
    // explicit hazard padding: VALU->MFMA srcA/B needs 2 cyc; MFMA(4-pass) dest -> any read
    // needs <=16 cyc. All nops INSIDE the asm so nothing schedules into the window.
    asm volatile("s_nop 1\n\t"
                 "v_mfma_f32_16x16x16_bf16 %0, %1, %2, %0\n\t"
                 "s_nop 7\n\t"
                 "s_nop 7"
                 : "+v"(c) : "v"(a), "v"(b));
    return c;
}
#endif

// w2t[n][j] = bf16(W2[j][n]);  mt[n][j] = bf16(M[j][n]), M[j][n] = W2[j][n]*sum_i W1[i][j]*W3[n][i]
__global__ void cnf_setup(const float* __restrict__ W1, const float* __restrict__ W2,
                          const float* __restrict__ W3,
                          unsigned short* __restrict__ w2t, unsigned short* __restrict__ mt) {
    const int j = blockIdx.x;
    const int n = threadIdx.x;
    float g = 0.0f;
#pragma unroll
    for (int i = 0; i < DIM; ++i) g = fmaf(W1[i * HID + j], W3[n * DIM + i], g);
    const float w2 = W2[j * HID + n];
    w2t[n * HID + j] = f2bf(w2);
    mt [n * HID + j] = f2bf(w2 * g);
}

__global__ __launch_bounds__(NTHR, 4) void cnf_main(
    const float* __restrict__ x,
    const float* __restrict__ W1, const float* __restrict__ b1,
    const float* __restrict__ b2, const float* __restrict__ b3,
    const unsigned short* __restrict__ w2t, const unsigned short* __restrict__ mt,
    const float* __restrict__ W3, float* __restrict__ out)
{
    __shared__ unsigned short zb[TILE_B][40];   // z-ext^T rows: 0..15 = z, 16 = t, 17 = 1.0, 18..31 = 0
                                                // physical col = logical col ^ (8*bit3(row))
    __shared__ unsigned short w3t[DIM][LSH];    // w3t[i][n] = W3[n][i]
    __shared__ unsigned short h1s[TILE_B][LSH]; // [b][n ^ 16*bit3(b)]
    __shared__ unsigned short d1s[TILE_B][LSH];
    __shared__ unsigned short d2s[TILE_B][LSH];
    __shared__ alignas(16) float fzp[8][2][16][20];  // fz partials [hwave][bt][b][i], stride 20
    __shared__ alignas(16) float divp[8][TILE_B];
    __shared__ alignas(16) float b2l[HID];
    __shared__ alignas(16) float b3l[DIM];

    const int tid  = (int)threadIdx.x;
    const int lane = tid & 63;
    const int wv   = tid >> 6;            // 0..15
    const int g    = lane >> 4;           // quad 0..3
    const int r    = lane & 15;
    const int g8   = g * 8;
    const int b0   = (int)blockIdx.x * TILE_B;
    const int swr  = ((r >> 3) & 1) << 4; // tile swizzle when row = bt*16+r (row bit3 = r bit3)
    const int zsw  = ((r >> 3) & 1) << 3; // zb swizzle (8-short granule)
    const int goff = g8 ^ swr;            // phase-2 read col offset
    const int n0w  = (wv & 7) * 32;

    // ---- phase-2 operand fragments (constant, in registers; R5 lesson: full unroll).
    bf16x8 breg[8][2];
    {
        const unsigned short* Bg = (wv < 8) ? w2t : mt;
#pragma unroll
        for (int k = 0; k < 8; ++k)
#pragma unroll
            for (int nt = 0; nt < 2; ++nt)
                breg[k][nt] = *(const bf16x8*)(Bg + (n0w + nt * 16 + r) * HID + k * 32 + g8);
    }

    // ---- phase-1 A-fragment (per-wave n-cols wv*16..+15): W1ext^T, b1 and t-row folded as K=16/17
    bf16x8 w1f;
    {
        const int n = wv * 16 + r;
#pragma unroll
        for (int e = 0; e < 8; ++e) {
            const int k = g8 + e;
            float v = 0.0f;
            if (k < 17)       v = W1[k * HID + n];   // k=16 is the t-row of W1
            else if (k == 17) v = b1[n];
            w1f[e] = (short)f2bf(v);
        }
    }

    // ---- update-wave (0/1) z-state: lane (r,g) holds z[b=wv*16+r][i=4g+q], fp32 ----
    float zb4[4] = {0, 0, 0, 0}, za4[4] = {0, 0, 0, 0};
    if (wv < 2) {
        const f32x4 xv = *(const f32x4*)&x[(b0 + wv * 16 + r) * DIM + 4 * g];
#pragma unroll
        for (int q = 0; q < 4; ++q) zb4[q] = xv[q];
        u32x2 pz = { (unsigned)f2bf(zb4[0]) | ((unsigned)f2bf(zb4[1]) << 16),
                     (unsigned)f2bf(zb4[2]) | ((unsigned)f2bf(zb4[3]) << 16) };
        *(u32x2*)&zb[wv * 16 + r][(4 * g) ^ zsw] = pz;
    }
    if (tid < TILE_B) {      // ext cols: t(=0 for stage 0), one, zeros
        const int zswi = ((tid >> 3) & 1) << 3;
#pragma unroll
        for (int c = 16; c < 32; ++c)
            zb[tid][c ^ zswi] = (c == 17) ? (unsigned short)0x3F80 : (unsigned short)0;
    }
    if (tid < 512) {         // w3t[i][n] = W3[n][i]
        const int n = tid >> 5, k0 = (tid & 31) * 8;
#pragma unroll
        for (int j = 0; j < 8; ++j) w3t[n][k0 + j] = f2bf(W3[(k0 + j) * DIM + n]);
    }
    if (tid < HID) b2l[tid] = b2[tid];   // biases live in LDS, not registers (R19)
    if (tid < DIM) b3l[tid] = b3[tid];

    __syncthreads();         // w3t ready: h-waves grab their fz A-fragments once
    bf16x4 w3f0 = {0, 0, 0, 0}, w3f1 = {0, 0, 0, 0};
    if (wv < 8) {            // A[i=r][k=4g+e] per nt-half: W3^T[i=r][n0w + nt*16 + 4g + e]
        w3f0 = *(const bf16x4*)&w3t[r][n0w + 4 * g];
        w3f1 = *(const bf16x4*)&w3t[r][n0w + 16 + 4 * g];
    }

    float lacc = 0.0f, logp = 0.0f;
    const float dt = 0.1f, dt6 = dt / 6.0f;

    for (int it = 0; it < NSTEPS * 4; ++it) {
        const int s = it & 3;
        const float wst = (s == 1 || s == 2) ? 2.0f : 1.0f;
        int opq = 0;
        asm volatile("" : "+v"(opq));    // opaque 0: blocks hoisting of per-stage bias reloads
        __syncthreads();   // B1: zb (z + t col) and prev-stage divp/fzp ready

        // ---------- deferred logp update for the PREVIOUS stage (wave 8) ----------
        if (wv == 8 && lane < TILE_B && it) {
            const int ps = (it + 3) & 3;
            const float pw = (ps == 1 || ps == 2) ? 2.0f : 1.0f;
            float dv = 0.0f;
#pragma unroll
            for (int w = 0; w < 8; ++w) dv += divp[w][lane];
            lacc = fmaf(-pw, dv, lacc);
            if (ps == 3) { logp = fmaf(dt6, lacc, logp); lacc = 0.0f; }
        }

        // ---------- phase 1 (all 16 waves, transposed): pre1^T[n][b] = W1ext^T @ zext^T
        //            -> h1,d1 packed b64 stores ----------
        {
            const bf16x8 bz0 = *(const bf16x8*)&zb[r][g8 ^ zsw];
            const bf16x8 bz1 = *(const bf16x8*)&zb[16 + r][g8 ^ zsw];
#pragma unroll
            for (int bt = 0; bt < 2; ++bt) {
                f32x4 c = {0.f, 0.f, 0.f, 0.f};
                c = __builtin_amdgcn_mfma_f32_16x16x32_bf16(w1f, bt ? bz1 : bz0, c, 0, 0, 0);
                float h[4], d[4];
#pragma unroll
                for (int q = 0; q < 4; ++q) silu_both(c[q], h[q], d[q]);
                const int row = bt * 16 + r;
                const int col = (wv * 16 + 4 * g) ^ swr;
                u32x2 hv  = { packtr(h[0], h[1]), packtr(h[2], h[3]) };
                u32x2 dv2 = { packtr(d[0], d[1]), packtr(d[2], d[3]) };
                *(u32x2*)&h1s[row][col] = hv;
                *(u32x2*)&d1s[row][col] = dv2;
            }
        }
        __syncthreads();   // B2: h1/d1 ready

        // ---------- phase 2 (operand-swapped MFMA): C[n][b], batch in lanes.
        //            A = breg (W2^T / M^T rows), B = h1/d1 rows ----------
        f32x4 cc[2][2];    // [nt][bt]; cc[nt][bt][q] = pre2[n0w+nt*16+4g+q][bt*16+r]
        {
            const unsigned short (*aT)[LSH] = (wv < 8) ? h1s : d1s;
#pragma unroll
            for (int a = 0; a < 2; ++a)
#pragma unroll
                for (int b = 0; b < 2; ++b) cc[a][b] = (f32x4){0.f, 0.f, 0.f, 0.f};
            __builtin_amdgcn_s_setprio(1);
#pragma unroll
            for (int k = 0; k < 8; ++k) {
                bf16x8 af[2];
#pragma unroll
                for (int bt = 0; bt < 2; ++bt)
                    af[bt] = *(const bf16x8*)&aT[bt * 16 + r][k * 32 + goff];
#pragma unroll
                for (int nt = 0; nt < 2; ++nt)
#pragma unroll
                    for (int bt = 0; bt < 2; ++bt)
                        cc[nt][bt] = __builtin_amdgcn_mfma_f32_16x16x32_bf16(breg[k][nt], af[bt], cc[nt][bt], 0, 0, 0);
            }
            __builtin_amdgcn_s_setprio(0);
        }
        // no barrier: d2s/fzp are fresh buffers this interval
        if (wv < 8) {
            // ---------- h-wave epilogue: silu -> d2s stores; h2 stays in registers and feeds
            //            the per-wave fz partial DIRECTLY: B[k=4g+e][b=r] of the K=16 MFMA is
            //            the lane's own silu output (no cross-lane movement) ----------
            const f32x4* bp20 = (const f32x4*)&b2l[n0w + 4 * g];
            const f32x4* bp21 = (const f32x4*)&b2l[n0w + 16 + 4 * g];
            const f32x4 bb0 = bp20[opq], bb1 = bp21[opq];   // per-stage reload, not registers
#pragma unroll
            for (int bt = 0; bt < 2; ++bt) {
                f32x4 cp = {0.f, 0.f, 0.f, 0.f};
#pragma unroll
                for (int nt = 0; nt < 2; ++nt) {
                    float h[4], d[4];
                    const f32x4 bb = nt ? bb1 : bb0;
#pragma unroll
                    for (int q = 0; q < 4; ++q) silu_both(cc[nt][bt][q] + bb[q], h[q], d[q]);
                    union { unsigned u[2]; bf16x4 v; } hb;
                    hb.u[0] = packtr(h[0], h[1]);
                    hb.u[1] = packtr(h[2], h[3]);
                    const int row = bt * 16 + r;
                    const int col = (n0w + nt * 16 + 4 * g) ^ swr;
                    *(u32x2*)&d2s[row][col] = (u32x2){ packtr(d[0], d[1]), packtr(d[2], d[3]) };
                    cp = mfma16(nt ? w3f1 : w3f0, hb.v, cp);   // K=16 partial: fz[i=4g+q][b=r]
                }
                *(f32x4*)&fzp[wv][bt][r][4 * g] = cp;   // [b][i], i contiguous
            }
        }
        __syncthreads();   // B4: d2s + fzp ready

        if (wv < 2) {
            // ---------- z-update (waves 0/1): sum 8 fz partials + b3, RK4, packed zb write ----
            __builtin_amdgcn_s_setprio(1);
            f32x4 fa = {0.f, 0.f, 0.f, 0.f}, fb = {0.f, 0.f, 0.f, 0.f};
#pragma unroll
            for (int w = 0; w < 8; w += 2) {
                fa += *(const f32x4*)&fzp[w][wv][r][4 * g];
                fb += *(const f32x4*)&fzp[w + 1][wv][r][4 * g];
            }
            const f32x4* bp3 = (const f32x4*)&b3l[4 * g];
            const f32x4 b3v = bp3[opq];                  // per-stage reload, not a register
            const float coef = (s == 2) ? dt : 0.5f * dt;
            float zn[4];
#pragma unroll
            for (int q = 0; q < 4; ++q) {
                const float fz = fa[q] + fb[q] + b3v[q];
                za4[q] = fmaf(wst, fz, za4[q]);
                if (s < 3) zn[q] = fmaf(coef, fz, zb4[q]);
                else { zb4[q] = fmaf(dt6, za4[q], zb4[q]); zn[q] = zb4[q]; za4[q] = 0.0f; }
            }
            u32x2 pz = { (unsigned)f2bf(zn[0]) | ((unsigned)f2bf(zn[1]) << 16),
                         (unsigned)f2bf(zn[2]) | ((unsigned)f2bf(zn[3]) << 16) };
            *(u32x2*)&zb[wv * 16 + r][(4 * g) ^ zsw] = pz;
            if (wv == 0 && lane < TILE_B) {      // publish t for next stage
                const int it1 = it + 1;
                const int s1 = it1 & 3;
                const float t1 = dt * (float)(it1 >> 2) + ((s1 == 0) ? 0.0f : (s1 == 3) ? dt : 0.5f * dt);
                zb[lane][16 ^ (((lane >> 3) & 1) << 3)] = f2bf(t1);
            }
            __builtin_amdgcn_s_setprio(0);
        } else if (wv >= 8) {
            // ---------- v-waves: div_b = sum_n d2[b][n]*v[n][b]; batch lane-local.
            //            4 packed b64 reads + 16 fma + 4 shfl ----------
            float p0 = 0.0f, p1 = 0.0f;
#pragma unroll
            for (int nt = 0; nt < 2; ++nt)
#pragma unroll
                for (int bt = 0; bt < 2; ++bt) {
                    const int row = bt * 16 + r;
                    const int col = (n0w + nt * 16 + 4 * g) ^ swr;
                    const u32x2 du = *(const u32x2*)&d2s[row][col];
                    float pp = (bt == 0) ? p0 : p1;
                    pp = fmaf(bfw_lo(du[0]), cc[nt][bt][0], pp);
                    pp = fmaf(bfw_hi(du[0]), cc[nt][bt][1], pp);
                    pp = fmaf(bfw_lo(du[1]), cc[nt][bt][2], pp);
                    pp = fmaf(bfw_hi(du[1]), cc[nt][bt][3], pp);
                    if (bt == 0) p0 = pp; else p1 = pp;
                }
            p0 += __shfl_xor(p0, 16, 64);
            p0 += __shfl_xor(p0, 32, 64);
            p1 += __shfl_xor(p1, 16, 64);
            p1 += __shfl_xor(p1, 32, 64);
            if (g < 2) divp[wv - 8][g * 16 + r] = g ? p1 : p0;
        }
        // (loop-top barrier covers zb, t-col, divp and fzp reuse)
    }

    // ---------- epilogue ----------
    __syncthreads();
    if (wv == 8 && lane < TILE_B) {   // flush last stage (s=3, weight 1) and publish logp
        float dv = 0.0f;
#pragma unroll
        for (int w = 0; w < 8; ++w) dv += divp[w][lane];
        lacc -= dv;
        logp = fmaf(dt6, lacc, logp);
        divp[0][lane] = logp;
    }
    __syncthreads();
    if (wv < 2) {
        float ss = zb4[0] * zb4[0] + zb4[1] * zb4[1] + zb4[2] * zb4[2] + zb4[3] * zb4[3];
        ss += __shfl_xor(ss, 16, 64);
        ss += __shfl_xor(ss, 32, 64);
        if (g == 0) {
            const int row = wv * 16 + r;
            out[b0 + row] = -0.5f * (ss + (float)DIM * 1.8378770664093453f) - divp[0][row];
        }
    }
}

extern "C" void kernel_launch(void* const* d_in, const int* in_sizes, int n_in,
                              void* d_out, int out_size, void* d_ws, size_t ws_size,
                              hipStream_t stream) {
    (void)in_sizes; (void)n_in; (void)out_size; (void)ws_size;
    const float* x  = (const float*)d_in[0];
    const float* W1 = (const float*)d_in[1];
    const float* b1 = (const float*)d_in[2];
    const float* W2 = (const float*)d_in[3];
    const float* b2 = (const float*)d_in[4];
    const float* W3 = (const float*)d_in[5];
    const float* b3 = (const float*)d_in[6];
    unsigned short* w2t = (unsigned short*)d_ws;               // 128 KB
    unsigned short* mt  = w2t + HID * HID;                     // 128 KB

    cnf_setup<<<HID, HID, 0, stream>>>(W1, W2, W3, w2t, mt);
    cnf_main<<<8192 / TILE_B, NTHR, 0, stream>>>(x, W1, b1, b2, b3, w2t, mt, W3, (float*)d_out);
}

// Round 9
// 192.309 us; speedup vs baseline: 1.0161x; 1.0161x over previous
//
#include <hip/hip_runtime.h>

#define DIM 16
#define HID 256
#define NSTEPS 10
#define TILE_B 32
#define NTHR 1024
#define LSH 264      // bf16 LDS row stride, multiple of 8 shorts (16 B) for aligned bf16x8 reads.
                     // Tile swizzle: stored col' = col ^ (16 * bit3(row)).
                     // R24: REGISTER DIET on the R23 structure. R23's parallel phase 3 worked but
                     // re-introduced in-loop spills (WRITE_SIZE 3->11 MB): h-waves gained w3f+cp
                     // while waves 0/1 also carry zb4/za4. Fixes: (a) w1f moved to LDS table
                     // w1e[256][40] (stride 40 shorts => only free 2-way r/r+8 aliasing), re-read
                     // per stage via the opq guard -- frees 4 VGPRs in ALL waves; (b) w3f0/w3f1
                     // re-read per stage from w3t (ds_read_b64, 2-way = free) -- frees 4 more in
                     // h-waves. Short live ranges instead of persistent registers. Structure,
                     // phases, barriers (3) unchanged from R23.

typedef __attribute__((ext_vector_type(8))) short bf16x8;
typedef __attribute__((ext_vector_type(4))) short bf16x4;
typedef __attribute__((ext_vector_type(4))) float f32x4;
typedef __attribute__((ext_vector_type(2))) unsigned int u32x2;

__device__ __forceinline__ unsigned short f2bf(float f) {
    unsigned u = __float_as_uint(f);
    u += 0x7fff + ((u >> 16) & 1);          // RNE
    return (unsigned short)(u >> 16);
}
__device__ __forceinline__ float bfw_lo(unsigned u) { return __uint_as_float(u << 16); }
__device__ __forceinline__ float bfw_hi(unsigned u) { return __uint_as_float(u & 0xffff0000u); }
__device__ __forceinline__ unsigned packtr(float a, float b) {   // [bf16(b):bf16(a)], trunc
    return __builtin_amdgcn_perm(__float_as_uint(b), __float_as_uint(a), 0x07060302u);
}
__device__ __forceinline__ void silu_both(float x, float& h, float& d) {
    float s = __builtin_amdgcn_rcpf(1.0f + __expf(-x));
    h = x * s;
    d = fmaf(h, 1.0f - s, s);               // silu' = s + h*(1-s)
}

#if defined(__has_builtin) && __has_builtin(__builtin_amdgcn_mfma_f32_16x16x16bf16_1k)
__device__ __forceinline__ f32x4 mfma16(bf16x4 a, bf16x4 b, f32x4 c) {
    return __builtin_amdgcn_mfma_f32_16x16x16bf16_1k(a, b, c, 0, 0, 0);
}
#else
__device__ __forceinline__ f32x4 mfma16(bf16x4 a, bf16x4 b, f32x4 c) {
    asm volatile("s_nop 1\n\t"
                 "v_mfma_f32_16x16x16_bf16 %0, %1, %2, %0\n\t"
                 "s_nop 7\n\t"
                 "s_nop 7"
                 : "+v"(c) : "v"(a), "v"(b));
    return c;
}
#endif

// w2t[n][j] = bf16(W2[j][n]);  mt[n][j] = bf16(M[j][n]), M[j][n] = W2[j][n]*sum_i W1[i][j]*W3[n][i]
__global__ void cnf_setup(const float* __restrict__ W1, const float* __restrict__ W2,
                          const float* __restrict__ W3,
                          unsigned short* __restrict__ w2t, unsigned short* __restrict__ mt) {
    const int j = blockIdx.x;
    const int n = threadIdx.x;
    float g = 0.0f;
#pragma unroll
    for (int i = 0; i < DIM; ++i) g = fmaf(W1[i * HID + j], W3[n * DIM + i], g);
    const float w2 = W2[j * HID + n];
    w2t[n * HID + j] = f2bf(w2);
    mt [n * HID + j] = f2bf(w2 * g);
}

__global__ __launch_bounds__(NTHR, 4) void cnf_main(
    const float* __restrict__ x,
    const float* __restrict__ W1, const float* __restrict__ b1,
    const float* __restrict__ b2, const float* __restrict__ b3,
    const unsigned short* __restrict__ w2t, const unsigned short* __restrict__ mt,
    const float* __restrict__ W3, float* __restrict__ out)
{
    __shared__ unsigned short zb[TILE_B][40];   // z-ext^T rows: 0..15 = z, 16 = t, 17 = 1.0, 18..31 = 0
                                                // physical col = logical col ^ (8*bit3(row))
    __shared__ unsigned short w1e[HID][40];     // W1ext^T rows n, cols k=0..31 (16=t-row, 17=b1, rest 0)
    __shared__ unsigned short w3t[DIM][LSH];    // w3t[i][n] = W3[n][i]
    __shared__ unsigned short h1s[TILE_B][LSH]; // [b][n ^ 16*bit3(b)]
    __shared__ unsigned short d1s[TILE_B][LSH];
    __shared__ unsigned short d2s[TILE_B][LSH];
    __shared__ alignas(16) float fzp[8][2][16][20];  // fz partials [hwave][bt][b][i], stride 20
    __shared__ alignas(16) float divp[8][TILE_B];
    __shared__ alignas(16) float b2l[HID];
    __shared__ alignas(16) float b3l[DIM];

    const int tid  = (int)threadIdx.x;
    const int lane = tid & 63;
    const int wv   = tid >> 6;            // 0..15
    const int g    = lane >> 4;           // quad 0..3
    const int r    = lane & 15;
    const int g8   = g * 8;
    const int b0   = (int)blockIdx.x * TILE_B;
    const int swr  = ((r >> 3) & 1) << 4; // tile swizzle when row = bt*16+r (row bit3 = r bit3)
    const int zsw  = ((r >> 3) & 1) << 3; // zb swizzle (8-short granule)
    const int goff = g8 ^ swr;            // phase-2 read col offset
    const int n0w  = (wv & 7) * 32;

    // ---- phase-2 operand fragments (constant, in registers; R5 lesson: full unroll).
    bf16x8 breg[8][2];
    {
        const unsigned short* Bg = (wv < 8) ? w2t : mt;
#pragma unroll
        for (int k = 0; k < 8; ++k)
#pragma unroll
            for (int nt = 0; nt < 2; ++nt)
                breg[k][nt] = *(const bf16x8*)(Bg + (n0w + nt * 16 + r) * HID + k * 32 + g8);
    }

    // ---- update-wave (0/1) z-state: lane (r,g) holds z[b=wv*16+r][i=4g+q], fp32 ----
    float zb4[4] = {0, 0, 0, 0}, za4[4] = {0, 0, 0, 0};
    if (wv < 2) {
        const f32x4 xv = *(const f32x4*)&x[(b0 + wv * 16 + r) * DIM + 4 * g];
#pragma unroll
        for (int q = 0; q < 4; ++q) zb4[q] = xv[q];
        u32x2 pz = { (unsigned)f2bf(zb4[0]) | ((unsigned)f2bf(zb4[1]) << 16),
                     (unsigned)f2bf(zb4[2]) | ((unsigned)f2bf(zb4[3]) << 16) };
        *(u32x2*)&zb[wv * 16 + r][(4 * g) ^ zsw] = pz;
    }
    if (tid < TILE_B) {      // ext cols: t(=0 for stage 0), one, zeros
        const int zswi = ((tid >> 3) & 1) << 3;
#pragma unroll
        for (int c = 16; c < 32; ++c)
            zb[tid][c ^ zswi] = (c == 17) ? (unsigned short)0x3F80 : (unsigned short)0;
    }
    {                        // w1e[n][k]: W1ext^T (one-time build, all 1024 threads)
        const int n = tid >> 2, kh = (tid & 3) * 8;
#pragma unroll
        for (int e = 0; e < 8; ++e) {
            const int k = kh + e;
            float v = 0.0f;
            if (k < 17)       v = W1[k * HID + n];   // k=16 is the t-row of W1
            else if (k == 17) v = b1[n];
            w1e[n][k] = f2bf(v);
        }
    }
    if (tid < 512) {         // w3t[i][n] = W3[n][i]
        const int n = tid >> 5, k0 = (tid & 31) * 8;
#pragma unroll
        for (int j = 0; j < 8; ++j) w3t[n][k0 + j] = f2bf(W3[(k0 + j) * DIM + n]);
    }
    if (tid < HID) b2l[tid] = b2[tid];   // biases live in LDS, not registers (R19)
    if (tid < DIM) b3l[tid] = b3[tid];

    float lacc = 0.0f, logp = 0.0f;
    const float dt = 0.1f, dt6 = dt / 6.0f;

    for (int it = 0; it < NSTEPS * 4; ++it) {
        const int s = it & 3;
        const float wst = (s == 1 || s == 2) ? 2.0f : 1.0f;
        int opq = 0;
        asm volatile("" : "+v"(opq));    // opaque 0: blocks hoisting of per-stage LDS reloads
        __syncthreads();   // B1: zb (z + t col), init tables, prev-stage divp/fzp ready

        // ---------- deferred logp update for the PREVIOUS stage (wave 8) ----------
        if (wv == 8 && lane < TILE_B && it) {
            const int ps = (it + 3) & 3;
            const float pw = (ps == 1 || ps == 2) ? 2.0f : 1.0f;
            float dv = 0.0f;
#pragma unroll
            for (int w = 0; w < 8; ++w) dv += divp[w][lane];
            lacc = fmaf(-pw, dv, lacc);
            if (ps == 3) { logp = fmaf(dt6, lacc, logp); lacc = 0.0f; }
        }

        // ---------- phase 1 (all 16 waves, transposed): pre1^T[n][b] = W1ext^T @ zext^T
        //            -> h1,d1 packed b64 stores. A-fragment re-read from LDS (short live range) --
        {
            const bf16x8* pw1 = (const bf16x8*)&w1e[wv * 16 + r][g8];
            const bf16x8 w1v = pw1[opq];
            const bf16x8 bz0 = *(const bf16x8*)&zb[r][g8 ^ zsw];
            const bf16x8 bz1 = *(const bf16x8*)&zb[16 + r][g8 ^ zsw];
#pragma unroll
            for (int bt = 0; bt < 2; ++bt) {
                f32x4 c = {0.f, 0.f, 0.f, 0.f};
                c = __builtin_amdgcn_mfma_f32_16x16x32_bf16(w1v, bt ? bz1 : bz0, c, 0, 0, 0);
                float h[4], d[4];
#pragma unroll
                for (int q = 0; q < 4; ++q) silu_both(c[q], h[q], d[q]);
                const int row = bt * 16 + r;
                const int col = (wv * 16 + 4 * g) ^ swr;
                u32x2 hv  = { packtr(h[0], h[1]), packtr(h[2], h[3]) };
                u32x2 dv2 = { packtr(d[0], d[1]), packtr(d[2], d[3]) };
                *(u32x2*)&h1s[row][col] = hv;
                *(u32x2*)&d1s[row][col] = dv2;
            }
        }
        __syncthreads();   // B2: h1/d1 ready

        // ---------- phase 2 (operand-swapped MFMA): C[n][b], batch in lanes.
        //            A = breg (W2^T / M^T rows), B = h1/d1 rows ----------
        f32x4 cc[2][2];    // [nt][bt]; cc[nt][bt][q] = pre2[n0w+nt*16+4g+q][bt*16+r]
        {
            const unsigned short (*aT)[LSH] = (wv < 8) ? h1s : d1s;
#pragma unroll
            for (int a = 0; a < 2; ++a)
#pragma unroll
                for (int b = 0; b < 2; ++b) cc[a][b] = (f32x4){0.f, 0.f, 0.f, 0.f};
            __builtin_amdgcn_s_setprio(1);
#pragma unroll
            for (int k = 0; k < 8; ++k) {
                bf16x8 af[2];
#pragma unroll
                for (int bt = 0; bt < 2; ++bt)
                    af[bt] = *(const bf16x8*)&aT[bt * 16 + r][k * 32 + goff];
#pragma unroll
                for (int nt = 0; nt < 2; ++nt)
#pragma unroll
                    for (int bt = 0; bt < 2; ++bt)
                        cc[nt][bt] = __builtin_amdgcn_mfma_f32_16x16x32_bf16(breg[k][nt], af[bt], cc[nt][bt], 0, 0, 0);
            }
            __builtin_amdgcn_s_setprio(0);
        }
        // no barrier: d2s/fzp are fresh buffers this interval
        if (wv < 8) {
            // ---------- h-wave epilogue: silu -> d2s stores; h2 stays in registers and feeds
            //            the per-wave fz partial DIRECTLY (K=16 MFMA, B = lane-local silu out).
            //            w3 A-fragments re-read from w3t each stage (short live range) ----------
            const f32x4* bp20 = (const f32x4*)&b2l[n0w + 4 * g];
            const f32x4* bp21 = (const f32x4*)&b2l[n0w + 16 + 4 * g];
            const f32x4 bb0 = bp20[opq], bb1 = bp21[opq];   // per-stage reload, not registers
            const bf16x4* pw3a = (const bf16x4*)&w3t[r][n0w + 4 * g];
            const bf16x4* pw3b = (const bf16x4*)&w3t[r][n0w + 16 + 4 * g];
            const bf16x4 w3fa = pw3a[opq], w3fb = pw3b[opq];
#pragma unroll
            for (int bt = 0; bt < 2; ++bt) {
                f32x4 cp = {0.f, 0.f, 0.f, 0.f};
#pragma unroll
                for (int nt = 0; nt < 2; ++nt) {
                    float h[4], d[4];
                    const f32x4 bb = nt ? bb1 : bb0;
#pragma unroll
                    for (int q = 0; q < 4; ++q) silu_both(cc[nt][bt][q] + bb[q], h[q], d[q]);
                    union { unsigned u[2]; bf16x4 v; } hb;
                    hb.u[0] = packtr(h[0], h[1]);
                    hb.u[1] = packtr(h[2], h[3]);
                    const int row = bt * 16 + r;
                    const int col = (n0w + nt * 16 + 4 * g) ^ swr;
                    *(u32x2*)&d2s[row][col] = (u32x2){ packtr(d[0], d[1]), packtr(d[2], d[3]) };
                    cp = mfma16(nt ? w3fb : w3fa, hb.v, cp);   // K=16 partial: fz[i=4g+q][b=r]
                }
                *(f32x4*)&fzp[wv][bt][r][4 * g] = cp;   // [b][i], i contiguous
            }
        }
        __syncthreads();   // B4: d2s + fzp ready

        if (wv < 2) {
            // ---------- z-update (waves 0/1): sum 8 fz partials + b3, RK4, packed zb write ----
            __builtin_amdgcn_s_setprio(1);
            f32x4 fa = {0.f, 0.f, 0.f, 0.f}, fb = {0.f, 0.f, 0.f, 0.f};
#pragma unroll
            for (int w = 0; w < 8; w += 2) {
                fa += *(const f32x4*)&fzp[w][wv][r][4 * g];
                fb += *(const f32x4*)&fzp[w + 1][wv][r][4 * g];
            }
            const f32x4* bp3 = (const f32x4*)&b3l[4 * g];
            const f32x4 b3v = bp3[opq];                  // per-stage reload, not a register
            const float coef = (s == 2) ? dt : 0.5f * dt;
            float zn[4];
#pragma unroll
            for (int q = 0; q < 4; ++q) {
                const float fz = fa[q] + fb[q] + b3v[q];
                za4[q] = fmaf(wst, fz, za4[q]);
                if (s < 3) zn[q] = fmaf(coef, fz, zb4[q]);
                else { zb4[q] = fmaf(dt6, za4[q], zb4[q]); zn[q] = zb4[q]; za4[q] = 0.0f; }
            }
            u32x2 pz = { (unsigned)f2bf(zn[0]) | ((unsigned)f2bf(zn[1]) << 16),
                         (unsigned)f2bf(zn[2]) | ((unsigned)f2bf(zn[3]) << 16) };
            *(u32x2*)&zb[wv * 16 + r][(4 * g) ^ zsw] = pz;
            if (wv == 0 && lane < TILE_B) {      // publish t for next stage
                const int it1 = it + 1;
                const int s1 = it1 & 3;
                const float t1 = dt * (float)(it1 >> 2) + ((s1 == 0) ? 0.0f : (s1 == 3) ? dt : 0.5f * dt);
                zb[lane][16 ^ (((lane >> 3) & 1) << 3)] = f2bf(t1);
            }
            __builtin_amdgcn_s_setprio(0);
        } else if (wv >= 8) {
            // ---------- v-waves: div_b = sum_n d2[b][n]*v[n][b]; batch lane-local.
            //            4 packed b64 reads + 16 fma + 4 shfl ----------
            float p0 = 0.0f, p1 = 0.0f;
#pragma unroll
            for (int nt = 0; nt < 2; ++nt)
#pragma unroll
                for (int bt = 0; bt < 2; ++bt) {
                    const int row = bt * 16 + r;
                    const int col = (n0w + nt * 16 + 4 * g) ^ swr;
                    const u32x2 du = *(const u32x2*)&d2s[row][col];
                    float pp = (bt == 0) ? p0 : p1;
                    pp = fmaf(bfw_lo(du[0]), cc[nt][bt][0], pp);
                    pp = fmaf(bfw_hi(du[0]), cc[nt][bt][1], pp);
                    pp = fmaf(bfw_lo(du[1]), cc[nt][bt][2], pp);
                    pp = fmaf(bfw_hi(du[1]), cc[nt][bt][3], pp);
                    if (bt == 0) p0 = pp; else p1 = pp;
                }
            p0 += __shfl_xor(p0, 16, 64);
            p0 += __shfl_xor(p0, 32, 64);
            p1 += __shfl_xor(p1, 16, 64);
            p1 += __shfl_xor(p1, 32, 64);
            if (g < 2) divp[wv - 8][g * 16 + r] = g ? p1 : p0;
        }
        // (loop-top barrier covers zb, t-col, divp and fzp reuse)
    }

    // ---------- epilogue ----------
    __syncthreads();
    if (wv == 8 && lane < TILE_B) {   // flush last stage (s=3, weight 1) and publish logp
        float dv = 0.0f;
#pragma unroll
        for (int w = 0; w < 8; ++w) dv += divp[w][lane];
        lacc -= dv;
        logp = fmaf(dt6, lacc, logp);
        divp[0][lane] = logp;
    }
    __syncthreads();
    if (wv < 2) {
        float ss = zb4[0] * zb4[0] + zb4[1] * zb4[1] + zb4[2] * zb4[2] + zb4[3] * zb4[3];
        ss += __shfl_xor(ss, 16, 64);
        ss += __shfl_xor(ss, 32, 64);
        if (g == 0) {
            const int row = wv * 16 + r;
            out[b0 + row] = -0.5f * (ss + (float)DIM * 1.8378770664093453f) - divp[0][row];
        }
    }
}

extern "C" void kernel_launch(void* const* d_in, const int* in_sizes, int n_in,
                              void* d_out, int out_size, void* d_ws, size_t ws_size,
                              hipStream_t stream) {
    (void)in_sizes; (void)n_in; (void)out_size; (void)ws_size;
    const float* x  = (const float*)d_in[0];
    const float* W1 = (const float*)d_in[1];
    const float* b1 = (const float*)d_in[2];
    const float* W2 = (const float*)d_in[3];
    const float* b2 = (const float*)d_in[4];
    const float* W3 = (const float*)d_in[5];
    const float* b3 = (const float*)d_in[6];
    unsigned short* w2t = (unsigned short*)d_ws;               // 128 KB
    unsigned short* mt  = w2t + HID * HID;                     // 128 KB

    cnf_setup<<<HID, HID, 0, stream>>>(W1, W2, W3, w2t, mt);
    cnf_main<<<8192 / TILE_B, NTHR, 0, stream>>>(x, W1, b1, b2, b3, w2t, mt, W3, (float*)d_out);
}

// Round 10
// 189.528 us; speedup vs baseline: 1.0310x; 1.0147x over previous
//
#include <hip/hip_runtime.h>

#define DIM 16
#define HID 256
#define NSTEPS 10
#define TILE_B 32
#define NTHR 1024
#define LSH 264      // bf16 LDS row stride, multiple of 8 shorts (16 B) for aligned bf16x8 reads.
                     // Tile swizzle: stored col' = col ^ (16 * bit3(row)).
                     // R25: (a) cnf_setup COALESCING -- old version had j=block, n=thread, making
                     // both 128 KB outputs stride-256 scattered b16 stores (the ~40 us gap between
                     // graded dur_us and cnf_main across every round). Swapped to n=block,
                     // j=thread: writes + W1 reads coalesced, W3 reads wave-uniform scalar.
                     // (b) breg global->AGPR load moved AFTER all LDS init and pinned with
                     // sched_barrier(0): its 64-VGPR in-flight transient no longer coexists with
                     // the w1e/w3t builds -- kills the remaining once-per-block init spills
                     // (WRITE_SIZE 9.2 MB -> expect <2.5 MB). Main loop is bit-identical to R24.

typedef __attribute__((ext_vector_type(8))) short bf16x8;
typedef __attribute__((ext_vector_type(4))) short bf16x4;
typedef __attribute__((ext_vector_type(4))) float f32x4;
typedef __attribute__((ext_vector_type(2))) unsigned int u32x2;

__device__ __forceinline__ unsigned short f2bf(float f) {
    unsigned u = __float_as_uint(f);
    u += 0x7fff + ((u >> 16) & 1);          // RNE
    return (unsigned short)(u >> 16);
}
__device__ __forceinline__ float bfw_lo(unsigned u) { return __uint_as_float(u << 16); }
__device__ __forceinline__ float bfw_hi(unsigned u) { return __uint_as_float(u & 0xffff0000u); }
__device__ __forceinline__ unsigned packtr(float a, float b) {   // [bf16(b):bf16(a)], trunc
    return __builtin_amdgcn_perm(__float_as_uint(b), __float_as_uint(a), 0x07060302u);
}
__device__ __forceinline__ void silu_both(float x, float& h, float& d) {
    float s = __builtin_amdgcn_rcpf(1.0f + __expf(-x));
    h = x * s;
    d = fmaf(h, 1.0f - s, s);               // silu' = s + h*(1-s)
}

#if defined(__has_builtin) && __has_builtin(__builtin_amdgcn_mfma_f32_16x16x16bf16_1k)
__device__ __forceinline__ f32x4 mfma16(bf16x4 a, bf16x4 b, f32x4 c) {
    return __builtin_amdgcn_mfma_f32_16x16x16bf16_1k(a, b, c, 0, 0, 0);
}
#else
__device__ __forceinline__ f32x4 mfma16(bf16x4 a, bf16x4 b, f32x4 c) {
    asm volatile("s_nop 1\n\t"
                 "v_mfma_f32_16x16x16_bf16 %0, %1, %2, %0\n\t"
                 "s_nop 7\n\t"
                 "s_nop 7"
                 : "+v"(c) : "v"(a), "v"(b));
    return c;
}
#endif

// w2t[n][j] = bf16(W2[j][n]);  mt[n][j] = bf16(M[j][n]), M[j][n] = W2[j][n]*sum_i W1[i][j]*W3[n][i]
// R25: n = blockIdx (row), j = threadIdx (col) -> w2t/mt writes and W1 reads coalesced,
// W3[n][i] reads wave-uniform (s_load broadcast). W2[j][n] reads strided but L2-resident.
__global__ void cnf_setup(const float* __restrict__ W1, const float* __restrict__ W2,
                          const float* __restrict__ W3,
                          unsigned short* __restrict__ w2t, unsigned short* __restrict__ mt) {
    const int n = blockIdx.x;
    const int j = threadIdx.x;
    float g = 0.0f;
#pragma unroll
    for (int i = 0; i < DIM; ++i) g = fmaf(W1[i * HID + j], W3[n * DIM + i], g);
    const float w2 = W2[j * HID + n];
    w2t[n * HID + j] = f2bf(w2);
    mt [n * HID + j] = f2bf(w2 * g);
}

__global__ __launch_bounds__(NTHR, 4) void cnf_main(
    const float* __restrict__ x,
    const float* __restrict__ W1, const float* __restrict__ b1,
    const float* __restrict__ b2, const float* __restrict__ b3,
    const unsigned short* __restrict__ w2t, const unsigned short* __restrict__ mt,
    const float* __restrict__ W3, float* __restrict__ out)
{
    __shared__ unsigned short zb[TILE_B][40];   // z-ext^T rows: 0..15 = z, 16 = t, 17 = 1.0, 18..31 = 0
                                                // physical col = logical col ^ (8*bit3(row))
    __shared__ unsigned short w1e[HID][40];     // W1ext^T rows n, cols k=0..31 (16=t-row, 17=b1, rest 0)
    __shared__ unsigned short w3t[DIM][LSH];    // w3t[i][n] = W3[n][i]
    __shared__ unsigned short h1s[TILE_B][LSH]; // [b][n ^ 16*bit3(b)]
    __shared__ unsigned short d1s[TILE_B][LSH];
    __shared__ unsigned short d2s[TILE_B][LSH];
    __shared__ alignas(16) float fzp[8][2][16][20];  // fz partials [hwave][bt][b][i], stride 20
    __shared__ alignas(16) float divp[8][TILE_B];
    __shared__ alignas(16) float b2l[HID];
    __shared__ alignas(16) float b3l[DIM];

    const int tid  = (int)threadIdx.x;
    const int lane = tid & 63;
    const int wv   = tid >> 6;            // 0..15
    const int g    = lane >> 4;           // quad 0..3
    const int r    = lane & 15;
    const int g8   = g * 8;
    const int b0   = (int)blockIdx.x * TILE_B;
    const int swr  = ((r >> 3) & 1) << 4; // tile swizzle when row = bt*16+r (row bit3 = r bit3)
    const int zsw  = ((r >> 3) & 1) << 3; // zb swizzle (8-short granule)
    const int goff = g8 ^ swr;            // phase-2 read col offset
    const int n0w  = (wv & 7) * 32;

    // ---- update-wave (0/1) z-state: lane (r,g) holds z[b=wv*16+r][i=4g+q], fp32 ----
    float zb4[4] = {0, 0, 0, 0}, za4[4] = {0, 0, 0, 0};
    if (wv < 2) {
        const f32x4 xv = *(const f32x4*)&x[(b0 + wv * 16 + r) * DIM + 4 * g];
#pragma unroll
        for (int q = 0; q < 4; ++q) zb4[q] = xv[q];
        u32x2 pz = { (unsigned)f2bf(zb4[0]) | ((unsigned)f2bf(zb4[1]) << 16),
                     (unsigned)f2bf(zb4[2]) | ((unsigned)f2bf(zb4[3]) << 16) };
        *(u32x2*)&zb[wv * 16 + r][(4 * g) ^ zsw] = pz;
    }
    if (tid < TILE_B) {      // ext cols: t(=0 for stage 0), one, zeros
        const int zswi = ((tid >> 3) & 1) << 3;
#pragma unroll
        for (int c = 16; c < 32; ++c)
            zb[tid][c ^ zswi] = (c == 17) ? (unsigned short)0x3F80 : (unsigned short)0;
    }
    {                        // w1e[n][k]: W1ext^T (one-time build, all 1024 threads)
        const int n = tid >> 2, kh = (tid & 3) * 8;
#pragma unroll
        for (int e = 0; e < 8; ++e) {
            const int k = kh + e;
            float v = 0.0f;
            if (k < 17)       v = W1[k * HID + n];   // k=16 is the t-row of W1
            else if (k == 17) v = b1[n];
            w1e[n][k] = f2bf(v);
        }
    }
    if (tid < 512) {         // w3t[i][n] = W3[n][i]
        const int n = tid >> 5, k0 = (tid & 31) * 8;
#pragma unroll
        for (int j = 0; j < 8; ++j) w3t[n][k0 + j] = f2bf(W3[(k0 + j) * DIM + n]);
    }
    if (tid < HID) b2l[tid] = b2[tid];   // biases live in LDS, not registers (R19)
    if (tid < DIM) b3l[tid] = b3[tid];

    // ---- phase-2 operand fragments (constant, -> AGPRs). Loaded AFTER all LDS init and
    //      pinned with sched_barrier so the 64-VGPR in-flight transient doesn't coexist
    //      with the init builds (R23/R24 init-time spills, 36 KB/block). ----
    __builtin_amdgcn_sched_barrier(0);
    bf16x8 breg[8][2];
    {
        const unsigned short* Bg = (wv < 8) ? w2t : mt;
#pragma unroll
        for (int k = 0; k < 8; ++k)
#pragma unroll
            for (int nt = 0; nt < 2; ++nt)
                breg[k][nt] = *(const bf16x8*)(Bg + (n0w + nt * 16 + r) * HID + k * 32 + g8);
    }
    __builtin_amdgcn_sched_barrier(0);

    float lacc = 0.0f, logp = 0.0f;
    const float dt = 0.1f, dt6 = dt / 6.0f;

    for (int it = 0; it < NSTEPS * 4; ++it) {
        const int s = it & 3;
        const float wst = (s == 1 || s == 2) ? 2.0f : 1.0f;
        int opq = 0;
        asm volatile("" : "+v"(opq));    // opaque 0: blocks hoisting of per-stage LDS reloads
        __syncthreads();   // B1: zb (z + t col), init tables, prev-stage divp/fzp ready

        // ---------- deferred logp update for the PREVIOUS stage (wave 8) ----------
        if (wv == 8 && lane < TILE_B && it) {
            const int ps = (it + 3) & 3;
            const float pw = (ps == 1 || ps == 2) ? 2.0f : 1.0f;
            float dv = 0.0f;
#pragma unroll
            for (int w = 0; w < 8; ++w) dv += divp[w][lane];
            lacc = fmaf(-pw, dv, lacc);
            if (ps == 3) { logp = fmaf(dt6, lacc, logp); lacc = 0.0f; }
        }

        // ---------- phase 1 (all 16 waves, transposed): pre1^T[n][b] = W1ext^T @ zext^T
        //            -> h1,d1 packed b64 stores. A-fragment re-read from LDS (short live range) --
        {
            const bf16x8* pw1 = (const bf16x8*)&w1e[wv * 16 + r][g8];
            const bf16x8 w1v = pw1[opq];
            const bf16x8 bz0 = *(const bf16x8*)&zb[r][g8 ^ zsw];
            const bf16x8 bz1 = *(const bf16x8*)&zb[16 + r][g8 ^ zsw];
#pragma unroll
            for (int bt = 0; bt < 2; ++bt) {
                f32x4 c = {0.f, 0.f, 0.f, 0.f};
                c = __builtin_amdgcn_mfma_f32_16x16x32_bf16(w1v, bt ? bz1 : bz0, c, 0, 0, 0);
                float h[4], d[4];
#pragma unroll
                for (int q = 0; q < 4; ++q) silu_both(c[q], h[q], d[q]);
                const int row = bt * 16 + r;
                const int col = (wv * 16 + 4 * g) ^ swr;
                u32x2 hv  = { packtr(h[0], h[1]), packtr(h[2], h[3]) };
                u32x2 dv2 = { packtr(d[0], d[1]), packtr(d[2], d[3]) };
                *(u32x2*)&h1s[row][col] = hv;
                *(u32x2*)&d1s[row][col] = dv2;
            }
        }
        __syncthreads();   // B2: h1/d1 ready

        // ---------- phase 2 (operand-swapped MFMA): C[n][b], batch in lanes.
        //            A = breg (W2^T / M^T rows), B = h1/d1 rows ----------
        f32x4 cc[2][2];    // [nt][bt]; cc[nt][bt][q] = pre2[n0w+nt*16+4g+q][bt*16+r]
        {
            const unsigned short (*aT)[LSH] = (wv < 8) ? h1s : d1s;
#pragma unroll
            for (int a = 0; a < 2; ++a)
#pragma unroll
                for (int b = 0; b < 2; ++b) cc[a][b] = (f32x4){0.f, 0.f, 0.f, 0.f};
            __builtin_amdgcn_s_setprio(1);
#pragma unroll
            for (int k = 0; k < 8; ++k) {
                bf16x8 af[2];
#pragma unroll
                for (int bt = 0; bt < 2; ++bt)
                    af[bt] = *(const bf16x8*)&aT[bt * 16 + r][k * 32 + goff];
#pragma unroll
                for (int nt = 0; nt < 2; ++nt)
#pragma unroll
                    for (int bt = 0; bt < 2; ++bt)
                        cc[nt][bt] = __builtin_amdgcn_mfma_f32_16x16x32_bf16(breg[k][nt], af[bt], cc[nt][bt], 0, 0, 0);
            }
            __builtin_amdgcn_s_setprio(0);
        }
        // no barrier: d2s/fzp are fresh buffers this interval
        if (wv < 8) {
            // ---------- h-wave epilogue: silu -> d2s stores; h2 stays in registers and feeds
            //            the per-wave fz partial DIRECTLY (K=16 MFMA, B = lane-local silu out).
            //            w3 A-fragments re-read from w3t each stage (short live range) ----------
            const f32x4* bp20 = (const f32x4*)&b2l[n0w + 4 * g];
            const f32x4* bp21 = (const f32x4*)&b2l[n0w + 16 + 4 * g];
            const f32x4 bb0 = bp20[opq], bb1 = bp21[opq];   // per-stage reload, not registers
            const bf16x4* pw3a = (const bf16x4*)&w3t[r][n0w + 4 * g];
            const bf16x4* pw3b = (const bf16x4*)&w3t[r][n0w + 16 + 4 * g];
            const bf16x4 w3fa = pw3a[opq], w3fb = pw3b[opq];
#pragma unroll
            for (int bt = 0; bt < 2; ++bt) {
                f32x4 cp = {0.f, 0.f, 0.f, 0.f};
#pragma unroll
                for (int nt = 0; nt < 2; ++nt) {
                    float h[4], d[4];
                    const f32x4 bb = nt ? bb1 : bb0;
#pragma unroll
                    for (int q = 0; q < 4; ++q) silu_both(cc[nt][bt][q] + bb[q], h[q], d[q]);
                    union { unsigned u[2]; bf16x4 v; } hb;
                    hb.u[0] = packtr(h[0], h[1]);
                    hb.u[1] = packtr(h[2], h[3]);
                    const int row = bt * 16 + r;
                    const int col = (n0w + nt * 16 + 4 * g) ^ swr;
                    *(u32x2*)&d2s[row][col] = (u32x2){ packtr(d[0], d[1]), packtr(d[2], d[3]) };
                    cp = mfma16(nt ? w3fb : w3fa, hb.v, cp);   // K=16 partial: fz[i=4g+q][b=r]
                }
                *(f32x4*)&fzp[wv][bt][r][4 * g] = cp;   // [b][i], i contiguous
            }
        }
        __syncthreads();   // B4: d2s + fzp ready

        if (wv < 2) {
            // ---------- z-update (waves 0/1): sum 8 fz partials + b3, RK4, packed zb write ----
            __builtin_amdgcn_s_setprio(1);
            f32x4 fa = {0.f, 0.f, 0.f, 0.f}, fb = {0.f, 0.f, 0.f, 0.f};
#pragma unroll
            for (int w = 0; w < 8; w += 2) {
                fa += *(const f32x4*)&fzp[w][wv][r][4 * g];
                fb += *(const f32x4*)&fzp[w + 1][wv][r][4 * g];
            }
            const f32x4* bp3 = (const f32x4*)&b3l[4 * g];
            const f32x4 b3v = bp3[opq];                  // per-stage reload, not a register
            const float coef = (s == 2) ? dt : 0.5f * dt;
            float zn[4];
#pragma unroll
            for (int q = 0; q < 4; ++q) {
                const float fz = fa[q] + fb[q] + b3v[q];
                za4[q] = fmaf(wst, fz, za4[q]);
                if (s < 3) zn[q] = fmaf(coef, fz, zb4[q]);
                else { zb4[q] = fmaf(dt6, za4[q], zb4[q]); zn[q] = zb4[q]; za4[q] = 0.0f; }
            }
            u32x2 pz = { (unsigned)f2bf(zn[0]) | ((unsigned)f2bf(zn[1]) << 16),
                         (unsigned)f2bf(zn[2]) | ((unsigned)f2bf(zn[3]) << 16) };
            *(u32x2*)&zb[wv * 16 + r][(4 * g) ^ zsw] = pz;
            if (wv == 0 && lane < TILE_B) {      // publish t for next stage
                const int it1 = it + 1;
                const int s1 = it1 & 3;
                const float t1 = dt * (float)(it1 >> 2) + ((s1 == 0) ? 0.0f : (s1 == 3) ? dt : 0.5f * dt);
                zb[lane][16 ^ (((lane >> 3) & 1) << 3)] = f2bf(t1);
            }
            __builtin_amdgcn_s_setprio(0);
        } else if (wv >= 8) {
            // ---------- v-waves: div_b = sum_n d2[b][n]*v[n][b]; batch lane-local.
            //            4 packed b64 reads + 16 fma + 4 shfl ----------
            float p0 = 0.0f, p1 = 0.0f;
#pragma unroll
            for (int nt = 0; nt < 2; ++nt)
#pragma unroll
                for (int bt = 0; bt < 2; ++bt) {
                    const int row = bt * 16 + r;
                    const int col = (n0w + nt * 16 + 4 * g) ^ swr;
                    const u32x2 du = *(const u32x2*)&d2s[row][col];
                    float pp = (bt == 0) ? p0 : p1;
                    pp = fmaf(bfw_lo(du[0]), cc[nt][bt][0], pp);
                    pp = fmaf(bfw_hi(du[0]), cc[nt][bt][1], pp);
                    pp = fmaf(bfw_lo(du[1]), cc[nt][bt][2], pp);
                    pp = fmaf(bfw_hi(du[1]), cc[nt][bt][3], pp);
                    if (bt == 0) p0 = pp; else p1 = pp;
                }
            p0 += __shfl_xor(p0, 16, 64);
            p0 += __shfl_xor(p0, 32, 64);
            p1 += __shfl_xor(p1, 16, 64);
            p1 += __shfl_xor(p1, 32, 64);
            if (g < 2) divp[wv - 8][g * 16 + r] = g ? p1 : p0;
        }
        // (loop-top barrier covers zb, t-col, divp and fzp reuse)
    }

    // ---------- epilogue ----------
    __syncthreads();
    if (wv == 8 && lane < TILE_B) {   // flush last stage (s=3, weight 1) and publish logp
        float dv = 0.0f;
#pragma unroll
        for (int w = 0; w < 8; ++w) dv += divp[w][lane];
        lacc -= dv;
        logp = fmaf(dt6, lacc, logp);
        divp[0][lane] = logp;
    }
    __syncthreads();
    if (wv < 2) {
        float ss = zb4[0] * zb4[0] + zb4[1] * zb4[1] + zb4[2] * zb4[2] + zb4[3] * zb4[3];
        ss += __shfl_xor(ss, 16, 64);
        ss += __shfl_xor(ss, 32, 64);
        if (g == 0) {
            const int row = wv * 16 + r;
            out[b0 + row] = -0.5f * (ss + (float)DIM * 1.8378770664093453f) - divp[0][row];
        }
    }
}

extern "C" void kernel_launch(void* const* d_in, const int* in_sizes, int n_in,
                              void* d_out, int out_size, void* d_ws, size_t ws_size,
                              hipStream_t stream) {
    (void)in_sizes; (void)n_in; (void)out_size; (void)ws_size;
    const float* x  = (const float*)d_in[0];
    const float* W1 = (const float*)d_in[1];
    const float* b1 = (const float*)d_in[2];
    const float* W2 = (const float*)d_in[3];
    const float* b2 = (const float*)d_in[4];
    const float* W3 = (const float*)d_in[5];
    const float* b3 = (const float*)d_in[6];
    unsigned short* w2t = (unsigned short*)d_ws;               // 128 KB
    unsigned short* mt  = w2t + HID * HID;                     // 128 KB

    cnf_setup<<<HID, HID, 0, stream>>>(W1, W2, W3, w2t, mt);
    cnf_main<<<8192 / TILE_B, NTHR, 0, stream>>>(x, W1, b1, b2, b3, w2t, mt, W3, (float*)d_out);
}

// Round 11
// 175.950 us; speedup vs baseline: 1.1105x; 1.0772x over previous
//
#include <hip/hip_runtime.h>

#define DIM 16
#define HID 256
#define NSTEPS 10
#define TILE_B 32
#define NTHR 1024
#define LSH 264      // bf16 LDS row stride (shorts) for d2s; fp8 tiles use 264-BYTE stride.
                     // R26: FP8 PHASE-2 OPERANDS. P2's 256 ds_read_b128/stage (8x redundant
                     // all-to-all of h1/d1) is the dominant LDS-pipe cost and is at the b128
                     // multi-pass floor -- only fewer bytes helps. h1,d1,W2,M -> OCP e4m3;
                     // mfma_f32_16x16x32_fp8_fp8 (same shape/rate, 2-reg operands). Reads halve
                     // to b64 (verified: stride 264B => bank 2(r+g), exactly 4 lanes/bank-pair =
                     // 4-pass minimum, no swizzle). breg 64->32 VGPRs (kills residual spills),
                     // LDS 105->88 KB. Precision: only the two inner matmul inputs are fp8;
                     // zb/W1/biases/h2/d2/fz and all f32 accumulation unchanged.

typedef __attribute__((ext_vector_type(8))) short bf16x8;
typedef __attribute__((ext_vector_type(4))) short bf16x4;
typedef __attribute__((ext_vector_type(4))) float f32x4;
typedef __attribute__((ext_vector_type(2))) unsigned int u32x2;

union F8x8 { unsigned u[2]; long long ll; };

__device__ __forceinline__ unsigned short f2bf(float f) {
    unsigned u = __float_as_uint(f);
    u += 0x7fff + ((u >> 16) & 1);          // RNE
    return (unsigned short)(u >> 16);
}
__device__ __forceinline__ float bfw_lo(unsigned u) { return __uint_as_float(u << 16); }
__device__ __forceinline__ float bfw_hi(unsigned u) { return __uint_as_float(u & 0xffff0000u); }
__device__ __forceinline__ unsigned packtr(float a, float b) {   // [bf16(b):bf16(a)], trunc
    return __builtin_amdgcn_perm(__float_as_uint(b), __float_as_uint(a), 0x07060302u);
}
__device__ __forceinline__ unsigned pk4_fp8(float a, float b, float c, float d) {
    int w = __builtin_amdgcn_cvt_pk_fp8_f32(a, b, 0, false);     // bytes 0,1
    w = __builtin_amdgcn_cvt_pk_fp8_f32(c, d, w, true);          // bytes 2,3
    return (unsigned)w;
}
__device__ __forceinline__ void silu_both(float x, float& h, float& d) {
    float s = __builtin_amdgcn_rcpf(1.0f + __expf(-x));
    h = x * s;
    d = fmaf(h, 1.0f - s, s);               // silu' = s + h*(1-s)
}

#if defined(__has_builtin) && __has_builtin(__builtin_amdgcn_mfma_f32_16x16x16bf16_1k)
__device__ __forceinline__ f32x4 mfma16(bf16x4 a, bf16x4 b, f32x4 c) {
    return __builtin_amdgcn_mfma_f32_16x16x16bf16_1k(a, b, c, 0, 0, 0);
}
#else
__device__ __forceinline__ f32x4 mfma16(bf16x4 a, bf16x4 b, f32x4 c) {
    asm volatile("s_nop 1\n\t"
                 "v_mfma_f32_16x16x16_bf16 %0, %1, %2, %0\n\t"
                 "s_nop 7\n\t"
                 "s_nop 7"
                 : "+v"(c) : "v"(a), "v"(b));
    return c;
}
#endif

// w2f8[n][j] = fp8(W2[j][n]);  mtf8[n][j] = fp8(M[j][n]), M[j][n] = W2[j][n]*sum_i W1[i][j]*W3[n][i]
// n = blockIdx (row), j = threadIdx (col): writes and W1 reads coalesced, W3 wave-uniform.
__global__ void cnf_setup(const float* __restrict__ W1, const float* __restrict__ W2,
                          const float* __restrict__ W3,
                          unsigned char* __restrict__ w2f8, unsigned char* __restrict__ mtf8) {
    const int n = blockIdx.x;
    const int j = threadIdx.x;
    float g = 0.0f;
#pragma unroll
    for (int i = 0; i < DIM; ++i) g = fmaf(W1[i * HID + j], W3[n * DIM + i], g);
    const float w2 = W2[j * HID + n];
    w2f8[n * HID + j] = (unsigned char)(__builtin_amdgcn_cvt_pk_fp8_f32(w2, w2, 0, false) & 0xff);
    const float m = w2 * g;
    mtf8[n * HID + j] = (unsigned char)(__builtin_amdgcn_cvt_pk_fp8_f32(m, m, 0, false) & 0xff);
}

__global__ __launch_bounds__(NTHR, 4) void cnf_main(
    const float* __restrict__ x,
    const float* __restrict__ W1, const float* __restrict__ b1,
    const float* __restrict__ b2, const float* __restrict__ b3,
    const unsigned char* __restrict__ w2f8, const unsigned char* __restrict__ mtf8,
    const float* __restrict__ W3, float* __restrict__ out)
{
    __shared__ unsigned short zb[TILE_B][40];   // z-ext^T rows: 0..15 = z, 16 = t, 17 = 1.0, 18..31 = 0
                                                // physical col = logical col ^ (8*bit3(row))
    __shared__ unsigned short w1e[HID][40];     // W1ext^T rows n, cols k=0..31 (16=t-row, 17=b1, rest 0)
    __shared__ unsigned short w3t[DIM][LSH];    // w3t[i][n] = W3[n][i]
    __shared__ unsigned char  h1f8[TILE_B][264];// fp8 h1 [b][n], 264-B stride (bank 2(r+g): no swizzle)
    __shared__ unsigned char  d1f8[TILE_B][264];
    __shared__ unsigned short d2s[TILE_B][LSH]; // bf16, col ^ 16*bit3(row) swizzle (unchanged)
    __shared__ alignas(16) float fzp[8][2][16][20];  // fz partials [hwave][bt][b][i], stride 20
    __shared__ alignas(16) float divp[8][TILE_B];
    __shared__ alignas(16) float b2l[HID];
    __shared__ alignas(16) float b3l[DIM];

    const int tid  = (int)threadIdx.x;
    const int lane = tid & 63;
    const int wv   = tid >> 6;            // 0..15
    const int g    = lane >> 4;           // quad 0..3
    const int r    = lane & 15;
    const int g8   = g * 8;
    const int b0   = (int)blockIdx.x * TILE_B;
    const int swr  = ((r >> 3) & 1) << 4; // d2s swizzle (row = bt*16+r)
    const int zsw  = ((r >> 3) & 1) << 3; // zb swizzle (8-short granule)
    const int n0w  = (wv & 7) * 32;

    // ---- update-wave (0/1) z-state: lane (r,g) holds z[b=wv*16+r][i=4g+q], fp32 ----
    float zb4[4] = {0, 0, 0, 0}, za4[4] = {0, 0, 0, 0};
    if (wv < 2) {
        const f32x4 xv = *(const f32x4*)&x[(b0 + wv * 16 + r) * DIM + 4 * g];
#pragma unroll
        for (int q = 0; q < 4; ++q) zb4[q] = xv[q];
        u32x2 pz = { (unsigned)f2bf(zb4[0]) | ((unsigned)f2bf(zb4[1]) << 16),
                     (unsigned)f2bf(zb4[2]) | ((unsigned)f2bf(zb4[3]) << 16) };
        *(u32x2*)&zb[wv * 16 + r][(4 * g) ^ zsw] = pz;
    }
    if (tid < TILE_B) {      // ext cols: t(=0 for stage 0), one, zeros
        const int zswi = ((tid >> 3) & 1) << 3;
#pragma unroll
        for (int c = 16; c < 32; ++c)
            zb[tid][c ^ zswi] = (c == 17) ? (unsigned short)0x3F80 : (unsigned short)0;
    }
    {                        // w1e[n][k]: W1ext^T (one-time build, all 1024 threads)
        const int n = tid >> 2, kh = (tid & 3) * 8;
#pragma unroll
        for (int e = 0; e < 8; ++e) {
            const int k = kh + e;
            float v = 0.0f;
            if (k < 17)       v = W1[k * HID + n];   // k=16 is the t-row of W1
            else if (k == 17) v = b1[n];
            w1e[n][k] = f2bf(v);
        }
    }
    if (tid < 512) {         // w3t[i][n] = W3[n][i]
        const int n = tid >> 5, k0 = (tid & 31) * 8;
#pragma unroll
        for (int j = 0; j < 8; ++j) w3t[n][k0 + j] = f2bf(W3[(k0 + j) * DIM + n]);
    }
    if (tid < HID) b2l[tid] = b2[tid];   // biases live in LDS, not registers (R19)
    if (tid < DIM) b3l[tid] = b3[tid];

    // ---- phase-2 operand fragments (fp8, 32 VGPRs total). Loaded after LDS init. ----
    __builtin_amdgcn_sched_barrier(0);
    u32x2 breg[8][2];
    {
        const unsigned char* Bg = (wv < 8) ? w2f8 : mtf8;
#pragma unroll
        for (int k = 0; k < 8; ++k)
#pragma unroll
            for (int nt = 0; nt < 2; ++nt)
                breg[k][nt] = *(const u32x2*)(Bg + (n0w + nt * 16 + r) * HID + k * 32 + g8);
    }
    __builtin_amdgcn_sched_barrier(0);

    float lacc = 0.0f, logp = 0.0f;
    const float dt = 0.1f, dt6 = dt / 6.0f;

    for (int it = 0; it < NSTEPS * 4; ++it) {
        const int s = it & 3;
        const float wst = (s == 1 || s == 2) ? 2.0f : 1.0f;
        int opq = 0;
        asm volatile("" : "+v"(opq));    // opaque 0: blocks hoisting of per-stage LDS reloads
        __syncthreads();   // B1: zb (z + t col), init tables, prev-stage divp/fzp ready

        // ---------- deferred logp update for the PREVIOUS stage (wave 8) ----------
        if (wv == 8 && lane < TILE_B && it) {
            const int ps = (it + 3) & 3;
            const float pw = (ps == 1 || ps == 2) ? 2.0f : 1.0f;
            float dv = 0.0f;
#pragma unroll
            for (int w = 0; w < 8; ++w) dv += divp[w][lane];
            lacc = fmaf(-pw, dv, lacc);
            if (ps == 3) { logp = fmaf(dt6, lacc, logp); lacc = 0.0f; }
        }

        // ---------- phase 1 (all 16 waves, transposed): pre1^T[n][b] = W1ext^T @ zext^T
        //            -> h1,d1 fp8, single b32 store each ----------
        {
            const bf16x8* pw1 = (const bf16x8*)&w1e[wv * 16 + r][g8];
            const bf16x8 w1v = pw1[opq];
            const bf16x8 bz0 = *(const bf16x8*)&zb[r][g8 ^ zsw];
            const bf16x8 bz1 = *(const bf16x8*)&zb[16 + r][g8 ^ zsw];
#pragma unroll
            for (int bt = 0; bt < 2; ++bt) {
                f32x4 c = {0.f, 0.f, 0.f, 0.f};
                c = __builtin_amdgcn_mfma_f32_16x16x32_bf16(w1v, bt ? bz1 : bz0, c, 0, 0, 0);
                float h[4], d[4];
#pragma unroll
                for (int q = 0; q < 4; ++q) silu_both(c[q], h[q], d[q]);
                const int row = bt * 16 + r;
                const int col = wv * 16 + 4 * g;           // byte col, dword-aligned
                *(unsigned*)&h1f8[row][col] = pk4_fp8(h[0], h[1], h[2], h[3]);
                *(unsigned*)&d1f8[row][col] = pk4_fp8(d[0], d[1], d[2], d[3]);
            }
        }
        __syncthreads();   // B2: h1/d1 ready

        // ---------- phase 2 (operand-swapped fp8 MFMA): C[n][b], batch in lanes.
        //            A = breg (W2^T / M^T rows, fp8), B = h1/d1 rows (b64 reads) ----------
        f32x4 cc[2][2];    // [nt][bt]; cc[nt][bt][q] = pre2[n0w+nt*16+4g+q][bt*16+r]
        {
            const unsigned char (*aT)[264] = (wv < 8) ? h1f8 : d1f8;
#pragma unroll
            for (int a = 0; a < 2; ++a)
#pragma unroll
                for (int b = 0; b < 2; ++b) cc[a][b] = (f32x4){0.f, 0.f, 0.f, 0.f};
            __builtin_amdgcn_s_setprio(1);
#pragma unroll
            for (int k = 0; k < 8; ++k) {
                F8x8 af[2];
#pragma unroll
                for (int bt = 0; bt < 2; ++bt)
                    af[bt] = *(const F8x8*)&aT[bt * 16 + r][k * 32 + g8];
#pragma unroll
                for (int nt = 0; nt < 2; ++nt) {
                    F8x8 av; av.u[0] = breg[k][nt][0]; av.u[1] = breg[k][nt][1];
#pragma unroll
                    for (int bt = 0; bt < 2; ++bt)
                        cc[nt][bt] = __builtin_amdgcn_mfma_f32_16x16x32_fp8_fp8(av.ll, af[bt].ll, cc[nt][bt], 0, 0, 0);
                }
            }
            __builtin_amdgcn_s_setprio(0);
        }
        // no barrier: d2s/fzp are fresh buffers this interval
        if (wv < 8) {
            // ---------- h-wave epilogue: silu -> d2s (bf16); h2 stays in registers and feeds
            //            the per-wave fz partial (K=16 MFMA, B = lane-local silu out) ----------
            const f32x4* bp20 = (const f32x4*)&b2l[n0w + 4 * g];
            const f32x4* bp21 = (const f32x4*)&b2l[n0w + 16 + 4 * g];
            const f32x4 bb0 = bp20[opq], bb1 = bp21[opq];   // per-stage reload, not registers
            const bf16x4* pw3a = (const bf16x4*)&w3t[r][n0w + 4 * g];
            const bf16x4* pw3b = (const bf16x4*)&w3t[r][n0w + 16 + 4 * g];
            const bf16x4 w3fa = pw3a[opq], w3fb = pw3b[opq];
#pragma unroll
            for (int bt = 0; bt < 2; ++bt) {
                f32x4 cp = {0.f, 0.f, 0.f, 0.f};
#pragma unroll
                for (int nt = 0; nt < 2; ++nt) {
                    float h[4], d[4];
                    const f32x4 bb = nt ? bb1 : bb0;
#pragma unroll
                    for (int q = 0; q < 4; ++q) silu_both(cc[nt][bt][q] + bb[q], h[q], d[q]);
                    union { unsigned u[2]; bf16x4 v; } hb;
                    hb.u[0] = packtr(h[0], h[1]);
                    hb.u[1] = packtr(h[2], h[3]);
                    const int row = bt * 16 + r;
                    const int col = (n0w + nt * 16 + 4 * g) ^ swr;
                    *(u32x2*)&d2s[row][col] = (u32x2){ packtr(d[0], d[1]), packtr(d[2], d[3]) };
                    cp = mfma16(nt ? w3fb : w3fa, hb.v, cp);   // K=16 partial: fz[i=4g+q][b=r]
                }
                *(f32x4*)&fzp[wv][bt][r][4 * g] = cp;   // [b][i], i contiguous
            }
        }
        __syncthreads();   // B4: d2s + fzp ready

        if (wv < 2) {
            // ---------- z-update (waves 0/1): sum 8 fz partials + b3, RK4, packed zb write ----
            __builtin_amdgcn_s_setprio(1);
            f32x4 fa = {0.f, 0.f, 0.f, 0.f}, fb = {0.f, 0.f, 0.f, 0.f};
#pragma unroll
            for (int w = 0; w < 8; w += 2) {
                fa += *(const f32x4*)&fzp[w][wv][r][4 * g];
                fb += *(const f32x4*)&fzp[w + 1][wv][r][4 * g];
            }
            const f32x4* bp3 = (const f32x4*)&b3l[4 * g];
            const f32x4 b3v = bp3[opq];                  // per-stage reload, not a register
            const float coef = (s == 2) ? dt : 0.5f * dt;
            float zn[4];
#pragma unroll
            for (int q = 0; q < 4; ++q) {
                const float fz = fa[q] + fb[q] + b3v[q];
                za4[q] = fmaf(wst, fz, za4[q]);
                if (s < 3) zn[q] = fmaf(coef, fz, zb4[q]);
                else { zb4[q] = fmaf(dt6, za4[q], zb4[q]); zn[q] = zb4[q]; za4[q] = 0.0f; }
            }
            u32x2 pz = { (unsigned)f2bf(zn[0]) | ((unsigned)f2bf(zn[1]) << 16),
                         (unsigned)f2bf(zn[2]) | ((unsigned)f2bf(zn[3]) << 16) };
            *(u32x2*)&zb[wv * 16 + r][(4 * g) ^ zsw] = pz;
            if (wv == 0 && lane < TILE_B) {      // publish t for next stage
                const int it1 = it + 1;
                const int s1 = it1 & 3;
                const float t1 = dt * (float)(it1 >> 2) + ((s1 == 0) ? 0.0f : (s1 == 3) ? dt : 0.5f * dt);
                zb[lane][16 ^ (((lane >> 3) & 1) << 3)] = f2bf(t1);
            }
            __builtin_amdgcn_s_setprio(0);
        } else if (wv >= 8) {
            // ---------- v-waves: div_b = sum_n d2[b][n]*v[n][b]; batch lane-local.
            //            4 packed b64 reads + 16 fma + 4 shfl ----------
            float p0 = 0.0f, p1 = 0.0f;
#pragma unroll
            for (int nt = 0; nt < 2; ++nt)
#pragma unroll
                for (int bt = 0; bt < 2; ++bt) {
                    const int row = bt * 16 + r;
                    const int col = (n0w + nt * 16 + 4 * g) ^ swr;
                    const u32x2 du = *(const u32x2*)&d2s[row][col];
                    float pp = (bt == 0) ? p0 : p1;
                    pp = fmaf(bfw_lo(du[0]), cc[nt][bt][0], pp);
                    pp = fmaf(bfw_hi(du[0]), cc[nt][bt][1], pp);
                    pp = fmaf(bfw_lo(du[1]), cc[nt][bt][2], pp);
                    pp = fmaf(bfw_hi(du[1]), cc[nt][bt][3], pp);
                    if (bt == 0) p0 = pp; else p1 = pp;
                }
            p0 += __shfl_xor(p0, 16, 64);
            p0 += __shfl_xor(p0, 32, 64);
            p1 += __shfl_xor(p1, 16, 64);
            p1 += __shfl_xor(p1, 32, 64);
            if (g < 2) divp[wv - 8][g * 16 + r] = g ? p1 : p0;
        }
        // (loop-top barrier covers zb, t-col, divp and fzp reuse)
    }

    // ---------- epilogue ----------
    __syncthreads();
    if (wv == 8 && lane < TILE_B) {   // flush last stage (s=3, weight 1) and publish logp
        float dv = 0.0f;
#pragma unroll
        for (int w = 0; w < 8; ++w) dv += divp[w][lane];
        lacc -= dv;
        logp = fmaf(dt6, lacc, logp);
        divp[0][lane] = logp;
    }
    __syncthreads();
    if (wv < 2) {
        float ss = zb4[0] * zb4[0] + zb4[1] * zb4[1] + zb4[2] * zb4[2] + zb4[3] * zb4[3];
        ss += __shfl_xor(ss, 16, 64);
        ss += __shfl_xor(ss, 32, 64);
        if (g == 0) {
            const int row = wv * 16 + r;
            out[b0 + row] = -0.5f * (ss + (float)DIM * 1.8378770664093453f) - divp[0][row];
        }
    }
}

extern "C" void kernel_launch(void* const* d_in, const int* in_sizes, int n_in,
                              void* d_out, int out_size, void* d_ws, size_t ws_size,
                              hipStream_t stream) {
    (void)in_sizes; (void)n_in; (void)out_size; (void)ws_size;
    const float* x  = (const float*)d_in[0];
    const float* W1 = (const float*)d_in[1];
    const float* b1 = (const float*)d_in[2];
    const float* W2 = (const float*)d_in[3];
    const float* b2 = (const float*)d_in[4];
    const float* W3 = (const float*)d_in[5];
    const float* b3 = (const float*)d_in[6];
    unsigned char* w2f8 = (unsigned char*)d_ws;                // 64 KB
    unsigned char* mtf8 = w2f8 + HID * HID;                    // 64 KB

    cnf_setup<<<HID, HID, 0, stream>>>(W1, W2, W3, w2f8, mtf8);
    cnf_main<<<8192 / TILE_B, NTHR, 0, stream>>>(x, W1, b1, b2, b3, w2f8, mtf8, W3, (float*)d_out);
}